// Round 8
// baseline (251.351 us; speedup 1.0000x reference)
//
#include <hip/hip_runtime.h>
#include <math.h>

#define BATCH 16
#define H 1024
#define W 1024
#define WSZ 11
#define OH (H - WSZ + 1)   // 1014
#define OW (W - WSZ + 1)   // 1014

// minmax config: exact cover
#define MM_BLOCKS 2048
#define MM_TPB 256
#define MM_PT 8            // float4 per thread per image; 2048*256*8 = NPIX/4 exactly

// tmqi config: one WAVE per 13-row strip, 16 cols/lane, zero LDS, zero barriers
#define TPB 256
#define RSTRIP 13          // 78 * 13 = 1014 exactly
#define NSTRIP (OH / RSTRIP)       // 78
#define NWAVES (NSTRIP * BATCH)    // 1248
#define TBLOCKS (NWAVES / 4)       // 312 blocks of 4 waves

// d_ws layout (all plain stores, no atomics):
//   [0, 16384)           : tmqi per-WAVE double partials (NWAVES*8 = 9984 B used)
//   [16384, +32768)      : minmax per-block float4 partials
//   [49152, +24)         : coef[6] folded scale constants
#define WS_DPART(ws)  ((double*)(ws))
#define WS_MMPART(ws) ((float4*)((char*)(ws) + 16384))
#define WS_COEF(ws)   ((float*)((char*)(ws) + 49152))

__device__ __forceinline__ float min4(float4 v) {
  return fminf(fminf(v.x, v.y), fminf(v.z, v.w));
}
__device__ __forceinline__ float max4(float4 v) {
  return fmaxf(fmaxf(v.x, v.y), fmaxf(v.z, v.w));
}

__global__ void __launch_bounds__(MM_TPB) minmax_kernel(
    const float4* __restrict__ a4, const float4* __restrict__ b4,
    float4* __restrict__ part) {
  const int tid = threadIdx.x;
  const size_t base = (size_t)blockIdx.x * (MM_TPB * MM_PT) + tid;
  float4 A0 = a4[base], A1 = a4[base + 256], A2 = a4[base + 512], A3 = a4[base + 768];
  float4 A4 = a4[base + 1024], A5 = a4[base + 1280], A6 = a4[base + 1536], A7 = a4[base + 1792];
  float4 B0 = b4[base], B1 = b4[base + 256], B2 = b4[base + 512], B3 = b4[base + 768];
  float4 B4 = b4[base + 1024], B5 = b4[base + 1280], B6 = b4[base + 1536], B7 = b4[base + 1792];
  float mn1 = fminf(fminf(fminf(min4(A0), min4(A1)), fminf(min4(A2), min4(A3))),
                    fminf(fminf(min4(A4), min4(A5)), fminf(min4(A6), min4(A7))));
  float mx1 = fmaxf(fmaxf(fmaxf(max4(A0), max4(A1)), fmaxf(max4(A2), max4(A3))),
                    fmaxf(fmaxf(max4(A4), max4(A5)), fmaxf(max4(A6), max4(A7))));
  float mn2 = fminf(fminf(fminf(min4(B0), min4(B1)), fminf(min4(B2), min4(B3))),
                    fminf(fminf(min4(B4), min4(B5)), fminf(min4(B6), min4(B7))));
  float mx2 = fmaxf(fmaxf(fmaxf(max4(B0), max4(B1)), fmaxf(max4(B2), max4(B3))),
                    fmaxf(fmaxf(max4(B4), max4(B5)), fmaxf(max4(B6), max4(B7))));
#pragma unroll
  for (int off = 32; off > 0; off >>= 1) {
    mn1 = fminf(mn1, __shfl_down(mn1, off));
    mx1 = fmaxf(mx1, __shfl_down(mx1, off));
    mn2 = fminf(mn2, __shfl_down(mn2, off));
    mx2 = fmaxf(mx2, __shfl_down(mx2, off));
  }
  __shared__ float s[4][4];
  const int wave = tid >> 6, lane = tid & 63;
  if (lane == 0) { s[0][wave] = mn1; s[1][wave] = mx1; s[2][wave] = mn2; s[3][wave] = mx2; }
  __syncthreads();
  if (tid == 0) {
    mn1 = fminf(fminf(s[0][0], s[0][1]), fminf(s[0][2], s[0][3]));
    mx1 = fmaxf(fmaxf(s[1][0], s[1][1]), fmaxf(s[1][2], s[1][3]));
    mn2 = fminf(fminf(s[2][0], s[2][1]), fminf(s[2][2], s[2][3]));
    mx2 = fmaxf(fmaxf(s[3][0], s[3][1]), fmaxf(s[3][2], s[3][3]));
    part[blockIdx.x] = make_float4(mn1, mx1, mn2, mx2);
  }
}

// 1 block: reduce 2048 float4 partials -> 6 folded coefs
__global__ void __launch_bounds__(256) reduce_minmax_kernel(
    const float4* __restrict__ part, float* __restrict__ coef) {
  const int tid = threadIdx.x;
  float mn1 = 1e30f, mx1 = -1e30f, mn2 = 1e30f, mx2 = -1e30f;
#pragma unroll
  for (int k = 0; k < MM_BLOCKS / 256; ++k) {
    float4 p = part[tid + k * 256];
    mn1 = fminf(mn1, p.x); mx1 = fmaxf(mx1, p.y);
    mn2 = fminf(mn2, p.z); mx2 = fmaxf(mx2, p.w);
  }
#pragma unroll
  for (int off = 32; off > 0; off >>= 1) {
    mn1 = fminf(mn1, __shfl_down(mn1, off));
    mx1 = fmaxf(mx1, __shfl_down(mx1, off));
    mn2 = fminf(mn2, __shfl_down(mn2, off));
    mx2 = fmaxf(mx2, __shfl_down(mx2, off));
  }
  __shared__ float s[4][4];
  const int wave = tid >> 6, lane = tid & 63;
  if (lane == 0) { s[0][wave] = mn1; s[1][wave] = mx1; s[2][wave] = mn2; s[3][wave] = mx2; }
  __syncthreads();
  if (tid == 0) {
    mn1 = fminf(fminf(s[0][0], s[0][1]), fminf(s[0][2], s[0][3]));
    mx1 = fmaxf(fmaxf(s[1][0], s[1][1]), fmaxf(s[1][2], s[1][3]));
    mn2 = fminf(fminf(s[2][0], s[2][1]), fminf(s[2][2], s[2][3]));
    mx2 = fmaxf(fmaxf(s[3][0], s[3][1]), fmaxf(s[3][2], s[3][3]));
    const float inv121 = 1.0f / 121.0f;
    float a1 = 255.0f / (mx1 - mn1 + 1e-6f);
    float a2 = 255.0f / (mx2 - mn2 + 1e-6f);
    coef[0] = a1 * a1 * inv121;
    coef[1] = a1 * a1 * inv121 * inv121;
    coef[2] = a2 * a2 * inv121;
    coef[3] = a2 * a2 * inv121 * inv121;
    coef[4] = a1 * a2 * inv121;
    coef[5] = a1 * a2 * inv121 * inv121;
  }
}

// load one row's 16 columns (4x float4) for both images
#define LOADROW(DU, DV, r) do {                                             \
    const float* _ru = p1 + ((size_t)(r) << 10);                            \
    const float* _rv = p2 + ((size_t)(r) << 10);                            \
    DU[0] = *(const float4*)(_ru + 0);  DU[1] = *(const float4*)(_ru + 4);  \
    DU[2] = *(const float4*)(_ru + 8);  DU[3] = *(const float4*)(_ru + 12); \
    DV[0] = *(const float4*)(_rv + 0);  DV[1] = *(const float4*)(_rv + 4);  \
    DV[2] = *(const float4*)(_rv + 8);  DV[3] = *(const float4*)(_rv + 12); \
  } while (0)

__device__ __forceinline__ void integ4(float S[5][16], int base, float4 u, float4 v) {
  float uu[4] = {u.x, u.y, u.z, u.w};
  float vv[4] = {v.x, v.y, v.z, v.w};
#pragma unroll
  for (int e = 0; e < 4; ++e) {
    float a = uu[e], bb = vv[e];
    S[0][base + e] += a;
    S[1][base + e] += bb;
    S[2][base + e] = fmaf(a, a, S[2][base + e]);
    S[3][base + e] = fmaf(bb, bb, S[3][base + e]);
    S[4][base + e] = fmaf(a, bb, S[4][base + e]);
  }
}

__device__ __forceinline__ void slide4(float S[5][16], int base,
                                       float4 un, float4 vn, float4 uo, float4 vo) {
  float a[4] = {un.x, un.y, un.z, un.w};
  float b[4] = {vn.x, vn.y, vn.z, vn.w};
  float c[4] = {uo.x, uo.y, uo.z, uo.w};
  float d[4] = {vo.x, vo.y, vo.z, vo.w};
#pragma unroll
  for (int e = 0; e < 4; ++e) {
    S[0][base + e] += a[e] - c[e];
    S[1][base + e] += b[e] - d[e];
    S[2][base + e] += fmaf(a[e], a[e], -c[e] * c[e]);
    S[3][base + e] += fmaf(b[e], b[e], -d[e] * d[e]);
    S[4][base + e] += fmaf(a[e], b[e], -c[e] * d[e]);
  }
}

__device__ __forceinline__ float mapfun(const float Wq[5],
                                        float cA2, float cA1, float cB2, float cB1,
                                        float cC2, float cC1,
                                        float uhdr, float inv_s, float Tsq) {
  float m1 = cA1 * Wq[0];
  float s1sq = fmaf(-m1, Wq[0], cA2 * Wq[2]);
  float m2 = cB1 * Wq[1];
  float s2sq = fmaf(-m2, Wq[1], cB2 * Wq[3]);
  float m3 = cC1 * Wq[0];
  float s12  = fmaf(-m3, Wq[1], cC2 * Wq[4]);
  float A  = fmaxf(s1sq, 0.0f) + 1e-6f;
  float Bq = fmaxf(s2sq, 0.0f) + 1e-6f;
  float sgp = __builtin_amdgcn_sqrtf(A * Bq);
  float smap = (s12 + 10.0f) * __builtin_amdgcn_rcpf(sgp + 10.0f);
  if (__builtin_expect(!(A >= Tsq && Bq >= Tsq), 0)) {
    // exact reference path (cold; erf saturation region never reached for this data)
    float sg1 = sqrtf(A), sg2 = sqrtf(Bq);
    float pp1 = 0.5f * (1.0f + erff((sg1 - uhdr) * inv_s));
    float pp2 = 0.5f * (1.0f + erff((sg2 - uhdr) * inv_s));
    float ratio1 = (2.0f * pp1 * pp2 + 0.01f) / (pp1 * pp1 + pp2 * pp2 + 0.01f);
    smap = ratio1 * ((s12 + 10.0f) / (sg1 * sg2 + 10.0f));
  }
  return smap;
}

// Wave-autonomous: no LDS, no __syncthreads. 1248 waves, 16 cols/lane.
__global__ void __launch_bounds__(TPB) tmqi_kernel(
    const float* __restrict__ img1, const float* __restrict__ img2,
    const float* __restrict__ coef, double* __restrict__ dpart,
    float uhdr, float inv_s, float Tsq) {
  const int tid = threadIdx.x;
  const int lane = tid & 63;
  const int wid = blockIdx.x * 4 + (tid >> 6);
  const int b = wid / NSTRIP;
  const int s = wid - b * NSTRIP;
  const int r0 = s * RSTRIP;
  const int c0 = lane * 16;

  const float cA2 = coef[0], cA1 = coef[1];
  const float cB2 = coef[2], cB1 = coef[3];
  const float cC2 = coef[4], cC1 = coef[5];

  const float* p1 = img1 + ((size_t)b << 20) + c0;
  const float* p2 = img2 + ((size_t)b << 20) + c0;

  float S[5][16];
#pragma unroll
  for (int j = 0; j < 16; ++j) {
    S[0][j] = S[1][j] = S[2][j] = S[3][j] = S[4][j] = 0.0f;
  }

  // prologue: rows r0..r0+10, 2-deep pipelined (static dbuf indices via full unroll)
  {
    float4 CU[2][4], CV[2][4];
    LOADROW(CU[0], CV[0], r0);
#pragma unroll
    for (int j = 0; j < WSZ; ++j) {
      const int p = j & 1;
      if (j + 1 < WSZ) LOADROW(CU[p ^ 1], CV[p ^ 1], r0 + j + 1);
#pragma unroll
      for (int c4 = 0; c4 < 4; ++c4) integ4(S, c4 * 4, CU[p][c4], CV[p][c4]);
    }
  }

  double acc = 0.0;

#pragma unroll 1
  for (int i = 0; i < RSTRIP; ++i) {
    float4 NU[4], NV[4], OU[4], OV[4];
    const bool more = (i + 1 < RSTRIP);
    if (more) {
      LOADROW(NU, NV, r0 + i + WSZ);  // new row (far: L3/HBM)
      LOADROW(OU, OV, r0 + i);        // old row (near: L1/L2, read 11 rows ago)
    }

    // horizontal running window + map, all in registers; neighbor cols via shfl
    float Wq[5];
#pragma unroll
    for (int q = 0; q < 5; ++q) {
      float t = S[q][0];
#pragma unroll
      for (int j = 1; j <= 10; ++j) t += S[q][j];
      Wq[q] = t;
    }
    float rowacc = mapfun(Wq, cA2, cA1, cB2, cB1, cC2, cC1, uhdr, inv_s, Tsq);  // k=0
#pragma unroll
    for (int k = 1; k < 16; ++k) {
#pragma unroll
      for (int q = 0; q < 5; ++q) {
        float add = (k + 10 < 16) ? S[q][k + 10] : __shfl_down(S[q][k - 6], 1);
        Wq[q] += add - S[q][k - 1];
      }
      float sm = mapfun(Wq, cA2, cA1, cB2, cB1, cC2, cC1, uhdr, inv_s, Tsq);
      // lanes 0..62 always valid; lane 63 valid for k<6 (c0=1008, OW=1014)
      rowacc += (c0 + k < OW) ? sm : 0.0f;
    }
    acc += (double)rowacc;

    if (more) {
#pragma unroll
      for (int c4 = 0; c4 < 4; ++c4)
        slide4(S, c4 * 4, NU[c4], NV[c4], OU[c4], OV[c4]);
    }
  }

  // wave-level reduce, one plain store per wave — no atomics, no LDS
#pragma unroll
  for (int off = 32; off > 0; off >>= 1) acc += __shfl_down(acc, off);
  if (lane == 0) dpart[wid] = acc;
}

// 1 block: sum NWAVES doubles, write final mean
__global__ void __launch_bounds__(256) finalize_kernel(
    const double* __restrict__ dpart, float* __restrict__ out) {
  const int tid = threadIdx.x;
  double acc = 0.0;
  for (int i = tid; i < NWAVES; i += 256) acc += dpart[i];
#pragma unroll
  for (int off = 32; off > 0; off >>= 1) acc += __shfl_down(acc, off);
  __shared__ double s[4];
  const int wave = tid >> 6, lane = tid & 63;
  if (lane == 0) s[wave] = acc;
  __syncthreads();
  if (tid == 0) {
    double total = s[0] + s[1] + s[2] + s[3];
    out[0] = (float)(total / (double)((size_t)BATCH * OH * OW));
  }
}

extern "C" void kernel_launch(void* const* d_in, const int* in_sizes, int n_in,
                              void* d_out, int out_size, void* d_ws, size_t ws_size,
                              hipStream_t stream) {
  const float* img1 = (const float*)d_in[0];
  const float* img2 = (const float*)d_in[1];
  float* out = (float*)d_out;

  double* dpart = WS_DPART(d_ws);
  float4* mmpart = WS_MMPART(d_ws);
  float* coef = WS_COEF(d_ws);

  const double csf = 100.0 * 2.6 * (0.0192 + 0.114 * 16.0) * exp(-pow(0.114 * 16.0, 1.1));
  const double u_hdr = 128.0 / (1.4 * csf);
  const double sig_hdr = u_hdr / 3.0;
  const float uhdr = (float)u_hdr;
  const float inv_s = (float)(1.0 / (sig_hdr * sqrt(2.0)));
  const double T = u_hdr + 4.0 * sig_hdr * sqrt(2.0);  // t>=4  <=>  A>=T^2
  const float Tsq = (float)(T * T);

  hipLaunchKernelGGL(minmax_kernel, dim3(MM_BLOCKS), dim3(MM_TPB), 0, stream,
                     (const float4*)img1, (const float4*)img2, mmpart);
  hipLaunchKernelGGL(reduce_minmax_kernel, dim3(1), dim3(256), 0, stream, mmpart, coef);
  hipLaunchKernelGGL(tmqi_kernel, dim3(TBLOCKS), dim3(TPB), 0, stream,
                     img1, img2, coef, dpart, uhdr, inv_s, Tsq);
  hipLaunchKernelGGL(finalize_kernel, dim3(1), dim3(256), 0, stream, dpart, out);
}